// Round 3
// baseline (367.183 us; speedup 1.0000x reference)
//
#include <hip/hip_runtime.h>
#include <hip/hip_bf16.h>
#include <stdint.h>
#include <stddef.h>

// Problem constants (fixed by the reference)
#define B_DIM 4
#define NH    16
#define LSEQ  2048
#define HD    64
#define DM    1024
#define TOKENS (B_DIM * LSEQ)   // 8192

typedef __bf16 bf16_t;
typedef __attribute__((ext_vector_type(8))) __bf16 bf16x8;
typedef __attribute__((ext_vector_type(4))) __bf16 bf16x4;
typedef __attribute__((ext_vector_type(4))) float  f32x4;

// async global->LDS, 16B per lane, lane i lands at ldsbase + i*16
#define GLD16(gp, lp) \
  __builtin_amdgcn_global_load_lds((__attribute__((address_space(1))) void*)(gp), \
                                   (__attribute__((address_space(3))) void*)(lp), 16, 0, 0)

__device__ __forceinline__ f32x4 mfma_16x16x32(bf16x8 a, bf16x8 b, f32x4 c) {
  return __builtin_amdgcn_mfma_f32_16x16x32_bf16(a, b, c, 0, 0, 0);
}

// ---------------------------------------------------------------------------
// Casts: 3 activations (dst contiguous: xq,xk,xv) / 4 weights (wq,wk,wv,wo)
// ---------------------------------------------------------------------------
__global__ __launch_bounds__(256) void cast3_kernel(const float* __restrict__ a,
                                                    const float* __restrict__ b,
                                                    const float* __restrict__ c,
                                                    bf16_t* __restrict__ dst, int n) {
  const float* src = (blockIdx.y == 0) ? a : (blockIdx.y == 1) ? b : c;
  const int i = (blockIdx.x * 256 + threadIdx.x) * 4;
  if (i < n) {
    const float4 v = *(const float4*)(src + i);
    bf16x4 o;
    o[0] = (bf16_t)v.x; o[1] = (bf16_t)v.y; o[2] = (bf16_t)v.z; o[3] = (bf16_t)v.w;
    *(bf16x4*)(dst + (size_t)blockIdx.y * n + i) = o;
  }
}

__global__ __launch_bounds__(256) void cast4_kernel(const float* __restrict__ a,
                                                    const float* __restrict__ b,
                                                    const float* __restrict__ c,
                                                    const float* __restrict__ d,
                                                    bf16_t* __restrict__ dst, int n) {
  const float* src = (blockIdx.y == 0) ? a : (blockIdx.y == 1) ? b
                   : (blockIdx.y == 2) ? c : d;
  const int i = (blockIdx.x * 256 + threadIdx.x) * 4;
  if (i < n) {
    const float4 v = *(const float4*)(src + i);
    bf16x4 o;
    o[0] = (bf16_t)v.x; o[1] = (bf16_t)v.y; o[2] = (bf16_t)v.z; o[3] = (bf16_t)v.w;
    *(bf16x4*)(dst + (size_t)blockIdx.y * n + i) = o;
  }
}

// ---------------------------------------------------------------------------
// Fused QKV projection: ONE dispatch, blockIdx.z in {0,1,2} = q,k,v.
// 128x128-tile bf16 GEMM, round-7 structure:
//  - LDS XOR-swizzle blk^=(row>>1)&3 via PRE-SWIZZLED GLOBAL source (T21:
//    gload_lds dest stays linear; read side XORs (l16>>1)&3). Kills the
//    6.29M bank conflicts (quarter-wave had 8 lanes on 4 banks).
//  - 2-deep LDS double-buffer (attn-v5 pipeline): prefetch next K-slab
//    before compute, ONE barrier/iter; its implicit vmcnt(0) drains a
//    prefetch that had the whole compute phase to land. 32KB LDS, still
//    4 blocks/CU (VGPR-capped).
// Epilogue: z<2 RoPE -> [B,NH,LSEQ,HD]; z==2 transposed -> [B,NH,HD,LSEQ].
// ---------------------------------------------------------------------------
__global__ __launch_bounds__(256) void qkv_proj_kernel(const bf16_t* __restrict__ X,
                                                       const bf16_t* __restrict__ Wb,
                                                       const float* __restrict__ bq,
                                                       const float* __restrict__ bk,
                                                       const float* __restrict__ bv,
                                                       const float* __restrict__ cos_q,
                                                       const float* __restrict__ sin_q,
                                                       const float* __restrict__ cos_k,
                                                       const float* __restrict__ sin_k,
                                                       bf16_t* __restrict__ qtb,
                                                       bf16_t* __restrict__ ktb,
                                                       bf16_t* __restrict__ vtb) {
  __shared__ bf16_t As[2][128 * 32];
  __shared__ bf16_t Bs[2][128 * 32];
  const int z = blockIdx.z;
  const bf16_t* A  = X  + (size_t)z * TOKENS * DM;
  const bf16_t* Bw = Wb + (size_t)z * DM * DM;
  const float* bias = (z == 0) ? bq : (z == 1) ? bk : bv;

  const int tid  = threadIdx.x;
  const int wave = tid >> 6, lane = tid & 63;
  const int quad = lane >> 4, l16 = lane & 15;
  const int m0 = blockIdx.x * 128, n0 = blockIdx.y * 128;
  const int wm = (wave >> 1) * 64, wn = (wave & 1) * 64;

  f32x4 acc[4][4];
#pragma unroll
  for (int i = 0; i < 4; ++i)
#pragma unroll
    for (int j = 0; j < 4; ++j) acc[i][j] = (f32x4){0.f, 0.f, 0.f, 0.f};

  // staging: lane covers LDS (row = c*16 + lane>>2, blk = lane&3); source
  // col-block pre-swizzled so LDS (row,blk) holds global blk^((row>>1)&3)
  const int srow = lane >> 2;
  const int scol = ((lane & 3) ^ ((lane >> 3) & 3)) * 8;
  const int c0 = wave * 2, c1 = c0 + 1;
  const int r0 = c0 * 16 + srow, r1 = c1 * 16 + srow;
  const bf16_t* Ag0 = A  + (size_t)(m0 + r0) * DM + scol;
  const bf16_t* Ag1 = A  + (size_t)(m0 + r1) * DM + scol;
  const bf16_t* Bg0 = Bw + (size_t)(n0 + r0) * DM + scol;
  const bf16_t* Bg1 = Bw + (size_t)(n0 + r1) * DM + scol;
  const int ld0 = c0 * 512, ld1 = c1 * 512;

  // fragment reads: XOR by (l16>>1)&3 (row = wm/wn + i*16 + l16; wm,16i == 0 mod 8)
  const int fcol = ((quad ^ ((l16 >> 1) & 3)) << 3);

  // prologue: stage K-slab 0 into buffer 0
  GLD16(Ag0, &As[0][0] + ld0); GLD16(Ag1, &As[0][0] + ld1);
  GLD16(Bg0, &Bs[0][0] + ld0); GLD16(Bg1, &Bs[0][0] + ld1);
  __syncthreads();

  int cur = 0;
  for (int t = 0; t < 32; ++t) {
    if (t < 31) {
      const int kk = (t + 1) * 32;
      bf16_t* Ad = &As[cur ^ 1][0];
      bf16_t* Bd = &Bs[cur ^ 1][0];
      GLD16(Ag0 + kk, Ad + ld0); GLD16(Ag1 + kk, Ad + ld1);
      GLD16(Bg0 + kk, Bd + ld0); GLD16(Bg1 + kk, Bd + ld1);
    }
    const bf16_t* Ac = &As[cur][0];
    const bf16_t* Bc = &Bs[cur][0];
    bf16x8 af[4], bfr[4];
#pragma unroll
    for (int i = 0; i < 4; ++i)
      af[i] = *(const bf16x8*)(Ac + (wm + i * 16 + l16) * 32 + fcol);
#pragma unroll
    for (int j = 0; j < 4; ++j)
      bfr[j] = *(const bf16x8*)(Bc + (wn + j * 16 + l16) * 32 + fcol);
#pragma unroll
    for (int i = 0; i < 4; ++i)
#pragma unroll
      for (int j = 0; j < 4; ++j)
        acc[i][j] = mfma_16x16x32(af[i], bfr[j], acc[i][j]);
    if (t < 31) __syncthreads();
    cur ^= 1;
  }

  // epilogue: C row = quad*4+reg, col = l16 (m89-verified C/D layout)
  if (z < 2) {
    const float* cosb = (z == 0) ? cos_q : cos_k;
    const float* sinb = (z == 0) ? sin_q : sin_k;
    bf16_t* out = (z == 0) ? qtb : ktb;
    const int h = (n0 + wn) >> 6;
#pragma unroll
    for (int i = 0; i < 4; ++i) {
#pragma unroll
      for (int j = 0; j < 2; ++j) {
        const int hd1 = j * 16 + l16;
        const int hd2 = hd1 + 32;
        const float bn1 = bias[n0 + wn + hd1];
        const float bn2 = bias[n0 + wn + hd2];
#pragma unroll
        for (int r = 0; r < 4; ++r) {
          const int m = m0 + wm + i * 16 + quad * 4 + r;
          const int b = m >> 11, l = m & (LSEQ - 1);
          const size_t cb = ((size_t)b * LSEQ + l) * HD;
          const float x1 = (float)(bf16_t)(acc[i][j][r] + bn1);
          const float x2 = (float)(bf16_t)(acc[i][j + 2][r] + bn2);
          const float c1 = cosb[cb + hd1], s1 = sinb[cb + hd1];
          const float c2 = cosb[cb + hd2], s2 = sinb[cb + hd2];
          bf16_t* dst = out + (((size_t)(b * NH + h)) * LSEQ + l) * HD;
          dst[hd1] = (bf16_t)(x1 * c1 - x2 * s1);
          dst[hd2] = (bf16_t)(x2 * c2 + x1 * s2);
        }
      }
    }
  } else {
#pragma unroll
    for (int i = 0; i < 4; ++i) {
      const int mb = m0 + wm + i * 16 + quad * 4;
      const int b = mb >> 11, l = mb & (LSEQ - 1);
#pragma unroll
      for (int j = 0; j < 4; ++j) {
        const int n = n0 + wn + j * 16 + l16;
        const int h = n >> 6, hd = n & (HD - 1);
        const float bn = bias[n];
        bf16x4 pk;
#pragma unroll
        for (int r = 0; r < 4; ++r) pk[r] = (bf16_t)(acc[i][j][r] + bn);
        *(bf16x4*)(vtb + (((size_t)(b * NH + h)) * HD + hd) * LSEQ + l) = pk;
      }
    }
  }
}

// ---------------------------------------------------------------------------
// Out projection: C = A * Wo^T + bo, f32 store (round-7: swizzle + dbuf)
// ---------------------------------------------------------------------------
__global__ __launch_bounds__(256) void out_gemm_kernel(const bf16_t* __restrict__ A,
                                                       const bf16_t* __restrict__ Bw,
                                                       const float* __restrict__ bias,
                                                       float* __restrict__ out) {
  __shared__ bf16_t As[2][128 * 32];
  __shared__ bf16_t Bs[2][128 * 32];
  const int tid  = threadIdx.x;
  const int wave = tid >> 6, lane = tid & 63;
  const int quad = lane >> 4, l16 = lane & 15;
  const int m0 = blockIdx.x * 128, n0 = blockIdx.y * 128;
  const int wm = (wave >> 1) * 64, wn = (wave & 1) * 64;

  f32x4 acc[4][4];
#pragma unroll
  for (int i = 0; i < 4; ++i)
#pragma unroll
    for (int j = 0; j < 4; ++j) acc[i][j] = (f32x4){0.f, 0.f, 0.f, 0.f};

  const int srow = lane >> 2;
  const int scol = ((lane & 3) ^ ((lane >> 3) & 3)) * 8;
  const int c0 = wave * 2, c1 = c0 + 1;
  const int r0 = c0 * 16 + srow, r1 = c1 * 16 + srow;
  const bf16_t* Ag0 = A  + (size_t)(m0 + r0) * DM + scol;
  const bf16_t* Ag1 = A  + (size_t)(m0 + r1) * DM + scol;
  const bf16_t* Bg0 = Bw + (size_t)(n0 + r0) * DM + scol;
  const bf16_t* Bg1 = Bw + (size_t)(n0 + r1) * DM + scol;
  const int ld0 = c0 * 512, ld1 = c1 * 512;
  const int fcol = ((quad ^ ((l16 >> 1) & 3)) << 3);

  GLD16(Ag0, &As[0][0] + ld0); GLD16(Ag1, &As[0][0] + ld1);
  GLD16(Bg0, &Bs[0][0] + ld0); GLD16(Bg1, &Bs[0][0] + ld1);
  __syncthreads();

  int cur = 0;
  for (int t = 0; t < 32; ++t) {
    if (t < 31) {
      const int kk = (t + 1) * 32;
      bf16_t* Ad = &As[cur ^ 1][0];
      bf16_t* Bd = &Bs[cur ^ 1][0];
      GLD16(Ag0 + kk, Ad + ld0); GLD16(Ag1 + kk, Ad + ld1);
      GLD16(Bg0 + kk, Bd + ld0); GLD16(Bg1 + kk, Bd + ld1);
    }
    const bf16_t* Ac = &As[cur][0];
    const bf16_t* Bc = &Bs[cur][0];
    bf16x8 af[4], bfr[4];
#pragma unroll
    for (int i = 0; i < 4; ++i)
      af[i] = *(const bf16x8*)(Ac + (wm + i * 16 + l16) * 32 + fcol);
#pragma unroll
    for (int j = 0; j < 4; ++j)
      bfr[j] = *(const bf16x8*)(Bc + (wn + j * 16 + l16) * 32 + fcol);
#pragma unroll
    for (int i = 0; i < 4; ++i)
#pragma unroll
      for (int j = 0; j < 4; ++j)
        acc[i][j] = mfma_16x16x32(af[i], bfr[j], acc[i][j]);
    if (t < 31) __syncthreads();
    cur ^= 1;
  }

#pragma unroll
  for (int i = 0; i < 4; ++i)
#pragma unroll
    for (int j = 0; j < 4; ++j) {
      const int n  = n0 + wn + j * 16 + l16;
      const float bn = bias[n];
#pragma unroll
      for (int r = 0; r < 4; ++r) {
        const int m = m0 + wm + i * 16 + quad * 4 + r;
        out[(size_t)m * DM + n] = acc[i][j][r] + bn;
      }
    }
}

// ---------------------------------------------------------------------------
// Flash attention v6 (unchanged from round 2): grid (LSEQ/128, B*NH),
// 256 threads (4 waves x 32 q-rows). sigma-permuted K staging, in-register
// P transpose, XOR swizzle, 2-deep buffer, mask pre-scan, l via ones-MFMA.
// ---------------------------------------------------------------------------
__global__ __launch_bounds__(256, 4) void attn_kernel(const bf16_t* __restrict__ qt,
                                                      const bf16_t* __restrict__ kt,
                                                      const bf16_t* __restrict__ vt,
                                                      const unsigned char* __restrict__ mask,
                                                      bf16_t* __restrict__ ctx) {
  __shared__ bf16_t Kl[2][64 * 64];        // [pos][d], col-blocks swizzled by pos&7
  __shared__ bf16_t Vl[2][64 * 64];        // [d][kk],  col-blocks swizzled by d&7
  __shared__ int mflag;
  const int bh = blockIdx.y;
  const int b = bh >> 4, h = bh & (NH - 1);
  const int q0 = blockIdx.x * 128;
  const int tid = threadIdx.x;
  const int wave = tid >> 6, lane = tid & 63;
  const int quad = lane >> 4, l16 = lane & 15;
  const float scale_l2e = 0.125f * 1.44269504f;  // HD^-0.5 * log2(e)

  const bf16_t* kbase = kt + (size_t)bh * LSEQ * HD;
  const bf16_t* vbase = vt + (size_t)bh * HD * LSEQ;
  const unsigned char* mrow = mask + (size_t)b * LSEQ;

  if (tid == 0) mflag = 0;
  __syncthreads();
  // mask pre-scan: 256 threads x 8B = entire 2048B row
  {
    const uint64_t mw = ((const uint64_t*)mrow)[tid];
    if (mw != 0) atomicOr(&mflag, 1);
  }

  // Q fragments (m=l16, k=quad*8+e), used as B-operand of swapped QK^T
  bf16x8 qa[2][2];
#pragma unroll
  for (int u = 0; u < 2; ++u) {
    const bf16_t* qrow = qt + (((size_t)bh * LSEQ) + q0 + wave * 32 + u * 16 + l16) * HD;
    qa[u][0] = *(const bf16x8*)(qrow + quad * 8);
    qa[u][1] = *(const bf16x8*)(qrow + 32 + quad * 8);
  }

  f32x4 O[2][4];
  f32x4 Ol[2];
#pragma unroll
  for (int u = 0; u < 2; ++u) {
    Ol[u] = (f32x4){0.f, 0.f, 0.f, 0.f};
#pragma unroll
    for (int j = 0; j < 4; ++j) O[u][j] = (f32x4){0.f, 0.f, 0.f, 0.f};
  }
  bf16x8 ones;
#pragma unroll
  for (int e = 0; e < 8; ++e) ones[e] = (bf16_t)1.0f;

  // --- hoisted per-lane offsets ---
  const int srow8 = lane >> 3;  // 0..7 within 8-row chunk
  const int scb   = lane & 7;   // LDS col-block position
  const int c0 = wave * 2, c1 = c0 + 1;
  const int p0 = c0 * 8 + srow8, p1 = p0 + 8;
  const int g0 = (scb ^ srow8) * 8;   // p&7 == srow8 for both chunks
  const int sig0 = ((p0 >> 5) << 5) | (((p0 >> 2) & 3) << 3) | (((p0 >> 4) & 1) << 2) | (p0 & 3);
  const int sig1 = ((p1 >> 5) << 5) | (((p1 >> 2) & 3) << 3) | (((p1 >> 4) & 1) << 2) | (p1 & 3);
  const int kgo0 = sig0 * HD + g0, kgo1 = sig1 * HD + g0;      // K global lane offsets
  const int vgo0 = p0 * LSEQ + g0, vgo1 = p1 * LSEQ + g0;      // V global lane offsets
  const int ld0 = c0 * 512, ld1 = c1 * 512;                    // LDS dst offsets

  // fragment-read offsets: sw = (j*16+l16)&7 == l16&7 for all j
  const int sw  = l16 & 7;
  const int oA  = l16 * 64 + ((quad ^ sw) << 3);
  const int oB  = l16 * 64 + (((quad + 4) ^ sw) << 3);

  // prologue: stage tile 0 into buffer 0 (K rows sigma-permuted)
  GLD16(kbase + kgo0, &Kl[0][0] + ld0);
  GLD16(kbase + kgo1, &Kl[0][0] + ld1);
  GLD16(vbase + vgo0, &Vl[0][0] + ld0);
  GLD16(vbase + vgo1, &Vl[0][0] + ld1);
  __syncthreads();
  const bool has_mask = (mflag != 0);

  int cur = 0;
  for (int t = 0; t < 32; ++t) {
    const int k0 = t * 64;

    // prefetch next tile into the other buffer (hidden under this tile's work)
    if (t < 31) {
      const int k0n = k0 + 64;
      bf16_t* Kd = &Kl[cur ^ 1][0];
      bf16_t* Vd = &Vl[cur ^ 1][0];
      GLD16(kbase + (size_t)k0n * HD + kgo0, Kd + ld0);
      GLD16(kbase + (size_t)k0n * HD + kgo1, Kd + ld1);
      GLD16(vbase + (size_t)(vgo0 + k0n), Vd + ld0);
      GLD16(vbase + (size_t)(vgo1 + k0n), Vd + ld1);
    }

    const bf16_t* Kc = &Kl[cur][0];
    const bf16_t* Vc = &Vl[cur][0];

    // S = exp2(scale*log2e * K.Q^T), swapped operands
    f32x4 S[2][4];
#pragma unroll
    for (int j = 0; j < 4; ++j) {
      const bf16x8 kb0 = *(const bf16x8*)(Kc + oA + j * 1024);
      const bf16x8 kb1 = *(const bf16x8*)(Kc + oB + j * 1024);
#pragma unroll
      for (int u = 0; u < 2; ++u) {
        f32x4 a = (f32x4){0.f, 0.f, 0.f, 0.f};
        a = mfma_16x16x32(kb0, qa[u][0], a);
        a = mfma_16x16x32(kb1, qa[u][1], a);
#pragma unroll
        for (int r = 0; r < 4; ++r)
          S[u][j][r] = __builtin_amdgcn_exp2f(a[r] * scale_l2e);
      }
    }

    // masked positions -> P = 0 (block-uniform skip when mask all-false)
    if (has_mask) {
      const uint64_t mlo = *(const uint64_t*)(mrow + k0 + quad * 8);
      const uint64_t mhi = *(const uint64_t*)(mrow + k0 + 32 + quad * 8);
      if (!__all((mlo | mhi) == 0)) {
#pragma unroll
        for (int j = 0; j < 4; ++j) {
          const uint64_t mm = (j & 2) ? mhi : mlo;
#pragma unroll
          for (int r = 0; r < 4; ++r)
            if ((mm >> (((j & 1) * 4 + r) * 8)) & 0xff) {
              S[0][j][r] = 0.f;
              S[1][j][r] = 0.f;
            }
        }
      }
    }

    // in-register P transpose: slot s=f*32+quad*8+e holds orig k=s
    bf16x8 pa[2][2];
#pragma unroll
    for (int u = 0; u < 2; ++u)
#pragma unroll
      for (int f = 0; f < 2; ++f)
#pragma unroll
        for (int e = 0; e < 8; ++e)
          pa[u][f][e] = (bf16_t)S[u][2 * f + (e >> 2)][e & 3];

    // l via ones-MFMA: every lane accumulates l(q) for q=quad*4+r in Ol[u][r]
#pragma unroll
    for (int u = 0; u < 2; ++u) {
      Ol[u] = mfma_16x16x32(pa[u][0], ones, Ol[u]);
      Ol[u] = mfma_16x16x32(pa[u][1], ones, Ol[u]);
    }

    // O += P * V  (B-operand from Vl [d][kk], swizzled); V frags reused for both u
#pragma unroll
    for (int jd = 0; jd < 4; ++jd) {
      const bf16x8 vb0 = *(const bf16x8*)(Vc + oA + jd * 1024);
      const bf16x8 vb1 = *(const bf16x8*)(Vc + oB + jd * 1024);
#pragma unroll
      for (int u = 0; u < 2; ++u) {
        O[u][jd] = mfma_16x16x32(pa[u][0], vb0, O[u][jd]);
        O[u][jd] = mfma_16x16x32(pa[u][1], vb1, O[u][jd]);
      }
    }

    // one barrier per tile: waves done reading buf[cur] AND (implicit
    // vmcnt(0)+lgkmcnt(0) drain) next-tile prefetch landed in buf[cur^1]
    if (t < 31) __syncthreads();
    cur ^= 1;
  }

  // epilogue: normalize and write ctx [B, LSEQ, NH*HD] bf16 (token-major)
#pragma unroll
  for (int u = 0; u < 2; ++u) {
    f32x4 linv;
#pragma unroll
    for (int r = 0; r < 4; ++r) linv[r] = 1.0f / Ol[u][r];
#pragma unroll
    for (int jd = 0; jd < 4; ++jd)
#pragma unroll
      for (int r = 0; r < 4; ++r) {
        const int l = q0 + wave * 32 + u * 16 + quad * 4 + r;
        const int d = h * HD + jd * 16 + l16;
        const float o = O[u][jd][r] * linv[r];
        ctx[((size_t)b * LSEQ + l) * DM + d] = (bf16_t)o;
      }
  }
}

// ---------------------------------------------------------------------------
extern "C" void kernel_launch(void* const* d_in, const int* in_sizes, int n_in,
                              void* d_out, int out_size, void* d_ws, size_t ws_size,
                              hipStream_t stream) {
  (void)in_sizes; (void)n_in; (void)out_size; (void)ws_size;
  const float* query = (const float*)d_in[0];
  const float* key   = (const float*)d_in[1];
  const float* value = (const float*)d_in[2];
  const float* cos_q = (const float*)d_in[3];
  const float* sin_q = (const float*)d_in[4];
  const float* cos_k = (const float*)d_in[5];
  const float* sin_k = (const float*)d_in[6];
  const unsigned char* mask = (const unsigned char*)d_in[7];
  const float* Wq = (const float*)d_in[8];
  const float* bq = (const float*)d_in[9];
  const float* Wk = (const float*)d_in[10];
  const float* bk = (const float*)d_in[11];
  const float* Wv = (const float*)d_in[12];
  const float* bv = (const float*)d_in[13];
  const float* Wo = (const float*)d_in[14];
  const float* bo = (const float*)d_in[15];
  float* out = (float*)d_out;

  const size_t ACT = (size_t)TOKENS * DM;  // 8388608
  const size_t WEL = (size_t)DM * DM;      // 1048576

  bf16_t* p   = (bf16_t*)d_ws;
  bf16_t* xq  = p; p += ACT;    // xq,xk,xv contiguous (cast3 dst / qkv A base)
  bf16_t* xk  = p; p += ACT;
  bf16_t* xv  = p; p += ACT;
  bf16_t* wqb = p; p += WEL;    // wqb..wob contiguous (cast4 dst / qkv W base)
  bf16_t* wkb = p; p += WEL;
  bf16_t* wvb = p; p += WEL;
  bf16_t* wob = p; p += WEL;
  bf16_t* qtb = p; p += ACT;
  bf16_t* ktb = p; p += ACT;
  bf16_t* vtb = p; p += ACT;
  bf16_t* ctx = xk;  // alias: xk dead after qkv proj
  (void)xv; (void)wkb; (void)wvb;

  // casts (f32 -> bf16): 2 dispatches
  cast3_kernel<<<dim3((int)(ACT / 1024), 3), 256, 0, stream>>>(query, key, value, xq, (int)ACT);
  cast4_kernel<<<dim3((int)(WEL / 1024), 4), 256, 0, stream>>>(Wq, Wk, Wv, Wo, wqb, (int)WEL);

  // fused q/k/v projections (one dispatch, z = which projection)
  qkv_proj_kernel<<<dim3(TOKENS / 128, DM / 128, 3), 256, 0, stream>>>(
      xq, wqb, bq, bk, bv, cos_q, sin_q, cos_k, sin_k, qtb, ktb, vtb);

  // flash attention -> ctx [B, LSEQ, DM] bf16
  attn_kernel<<<dim3(LSEQ / 128, B_DIM * NH), 256, 0, stream>>>(qtb, ktb, vtb, mask, ctx);

  // output projection -> f32 d_out
  out_gemm_kernel<<<dim3(TOKENS / 128, DM / 128), 256, 0, stream>>>(ctx, wob, bo, out);
}

// Round 4
// 359.940 us; speedup vs baseline: 1.0201x; 1.0201x over previous
//
#include <hip/hip_runtime.h>
#include <hip/hip_bf16.h>
#include <stdint.h>
#include <stddef.h>

// Problem constants (fixed by the reference)
#define B_DIM 4
#define NH    16
#define LSEQ  2048
#define HD    64
#define DM    1024
#define TOKENS (B_DIM * LSEQ)   // 8192

typedef __bf16 bf16_t;
typedef __attribute__((ext_vector_type(8))) __bf16 bf16x8;
typedef __attribute__((ext_vector_type(4))) __bf16 bf16x4;
typedef __attribute__((ext_vector_type(4))) float  f32x4;

// async global->LDS, 16B per lane, lane i lands at ldsbase + i*16
#define GLD16(gp, lp) \
  __builtin_amdgcn_global_load_lds((__attribute__((address_space(1))) void*)(gp), \
                                   (__attribute__((address_space(3))) void*)(lp), 16, 0, 0)

// raw sync primitives (T4: counted vmcnt, NEVER vmcnt(0) drain in main loop)
#define WAITV4 asm volatile("s_waitcnt vmcnt(4)" ::: "memory")
#define WAITV0 asm volatile("s_waitcnt vmcnt(0)" ::: "memory")
#define WAITL0 asm volatile("s_waitcnt lgkmcnt(0)" ::: "memory")
#define SBAR   __builtin_amdgcn_s_barrier()
#define SCHED0 __builtin_amdgcn_sched_barrier(0)

__device__ __forceinline__ f32x4 mfma_16x16x32(bf16x8 a, bf16x8 b, f32x4 c) {
  return __builtin_amdgcn_mfma_f32_16x16x32_bf16(a, b, c, 0, 0, 0);
}

// ---------------------------------------------------------------------------
// Casts: 3 activations (dst contiguous: xq,xk,xv) / 4 weights (wq,wk,wv,wo)
// ---------------------------------------------------------------------------
__global__ __launch_bounds__(256) void cast3_kernel(const float* __restrict__ a,
                                                    const float* __restrict__ b,
                                                    const float* __restrict__ c,
                                                    bf16_t* __restrict__ dst, int n) {
  const float* src = (blockIdx.y == 0) ? a : (blockIdx.y == 1) ? b : c;
  const int i = (blockIdx.x * 256 + threadIdx.x) * 4;
  if (i < n) {
    const float4 v = *(const float4*)(src + i);
    bf16x4 o;
    o[0] = (bf16_t)v.x; o[1] = (bf16_t)v.y; o[2] = (bf16_t)v.z; o[3] = (bf16_t)v.w;
    *(bf16x4*)(dst + (size_t)blockIdx.y * n + i) = o;
  }
}

__global__ __launch_bounds__(256) void cast4_kernel(const float* __restrict__ a,
                                                    const float* __restrict__ b,
                                                    const float* __restrict__ c,
                                                    const float* __restrict__ d,
                                                    bf16_t* __restrict__ dst, int n) {
  const float* src = (blockIdx.y == 0) ? a : (blockIdx.y == 1) ? b
                   : (blockIdx.y == 2) ? c : d;
  const int i = (blockIdx.x * 256 + threadIdx.x) * 4;
  if (i < n) {
    const float4 v = *(const float4*)(src + i);
    bf16x4 o;
    o[0] = (bf16_t)v.x; o[1] = (bf16_t)v.y; o[2] = (bf16_t)v.z; o[3] = (bf16_t)v.w;
    *(bf16x4*)(dst + (size_t)blockIdx.y * n + i) = o;
  }
}

// GEMM tile body (shared by qkv/out): counted-vmcnt double-buffer pipeline.
// WAIT: this tile's 4 loads are the OLDEST outstanding -> vmcnt(4) suffices
// (vmcnt(0) only for the very last tile). Prefetch of tile i+2 is issued
// AFTER the read-done barrier and has a full iteration to land.
#define GEMM_TILE(CUR, WAIT, PRE, KK2)                                        \
  {                                                                           \
    WAIT; SBAR; SCHED0;                                                       \
    const bf16_t* Ac = &As[CUR][0];                                           \
    const bf16_t* Bc = &Bs[CUR][0];                                           \
    bf16x8 af[4], bfr[4];                                                     \
    _Pragma("unroll") for (int i_ = 0; i_ < 4; ++i_)                          \
      af[i_] = *(const bf16x8*)(Ac + (wm + i_ * 16 + l16) * 32 + fcol);       \
    _Pragma("unroll") for (int j_ = 0; j_ < 4; ++j_)                          \
      bfr[j_] = *(const bf16x8*)(Bc + (wn + j_ * 16 + l16) * 32 + fcol);      \
    _Pragma("unroll") for (int i_ = 0; i_ < 4; ++i_)                          \
      _Pragma("unroll") for (int j_ = 0; j_ < 4; ++j_)                        \
        acc[i_][j_] = mfma_16x16x32(af[i_], bfr[j_], acc[i_][j_]);            \
    WAITL0; SBAR; SCHED0;                                                     \
    if (PRE) {                                                                \
      const int kk2_ = (KK2);                                                 \
      GLD16(Ag0 + kk2_, &As[CUR][0] + ld0);                                   \
      GLD16(Ag1 + kk2_, &As[CUR][0] + ld1);                                   \
      GLD16(Bg0 + kk2_, &Bs[CUR][0] + ld0);                                   \
      GLD16(Bg1 + kk2_, &Bs[CUR][0] + ld1);                                   \
    }                                                                         \
  }

// ---------------------------------------------------------------------------
// Fused QKV projection: ONE dispatch, blockIdx.z in {0,1,2} = q,k,v.
// 128x128-tile bf16 GEMM, round-8 structure:
//  - LDS XOR-swizzle blk^=(row>>1)&3 via pre-swizzled global source (T21);
//    round-3 verified: bank conflicts 6.29M -> 0.
//  - counted-vmcnt 2-deep pipeline (T4): raw s_barrier + vmcnt(4), loads for
//    tile i+2 stay in flight across both barriers; NO vmcnt(0) drain in loop
//    (round-3's __syncthreads drain was the regression). Buffer index is a
//    compile-time literal (manual 2x unroll) - no runtime cur select.
// Epilogue: z<2 RoPE -> [B,NH,LSEQ,HD]; z==2 transposed -> [B,NH,HD,LSEQ].
// ---------------------------------------------------------------------------
__global__ __launch_bounds__(256) void qkv_proj_kernel(const bf16_t* __restrict__ X,
                                                       const bf16_t* __restrict__ Wb,
                                                       const float* __restrict__ bq,
                                                       const float* __restrict__ bk,
                                                       const float* __restrict__ bv,
                                                       const float* __restrict__ cos_q,
                                                       const float* __restrict__ sin_q,
                                                       const float* __restrict__ cos_k,
                                                       const float* __restrict__ sin_k,
                                                       bf16_t* __restrict__ qtb,
                                                       bf16_t* __restrict__ ktb,
                                                       bf16_t* __restrict__ vtb) {
  __shared__ bf16_t As[2][128 * 32];
  __shared__ bf16_t Bs[2][128 * 32];
  const int z = blockIdx.z;
  const bf16_t* A  = X  + (size_t)z * TOKENS * DM;
  const bf16_t* Bw = Wb + (size_t)z * DM * DM;
  const float* bias = (z == 0) ? bq : (z == 1) ? bk : bv;

  const int tid  = threadIdx.x;
  const int wave = tid >> 6, lane = tid & 63;
  const int quad = lane >> 4, l16 = lane & 15;
  const int m0 = blockIdx.x * 128, n0 = blockIdx.y * 128;
  const int wm = (wave >> 1) * 64, wn = (wave & 1) * 64;

  f32x4 acc[4][4];
#pragma unroll
  for (int i = 0; i < 4; ++i)
#pragma unroll
    for (int j = 0; j < 4; ++j) acc[i][j] = (f32x4){0.f, 0.f, 0.f, 0.f};

  // staging: lane covers LDS (row = c*16 + lane>>2, blk = lane&3); source
  // col-block pre-swizzled so LDS (row,blk) holds global blk^((row>>1)&3)
  const int srow = lane >> 2;
  const int scol = ((lane & 3) ^ ((lane >> 3) & 3)) * 8;
  const int c0 = wave * 2, c1 = c0 + 1;
  const int r0 = c0 * 16 + srow, r1 = c1 * 16 + srow;
  const bf16_t* Ag0 = A  + (size_t)(m0 + r0) * DM + scol;
  const bf16_t* Ag1 = A  + (size_t)(m0 + r1) * DM + scol;
  const bf16_t* Bg0 = Bw + (size_t)(n0 + r0) * DM + scol;
  const bf16_t* Bg1 = Bw + (size_t)(n0 + r1) * DM + scol;
  const int ld0 = c0 * 512, ld1 = c1 * 512;

  // fragment reads: XOR by (l16>>1)&3 (row = wm/wn + i*16 + l16; wm,16i == 0 mod 8)
  const int fcol = ((quad ^ ((l16 >> 1) & 3)) << 3);

  // prologue: tiles 0 and 1 (8 loads in flight; tile 0's are the oldest 4)
  GLD16(Ag0, &As[0][0] + ld0); GLD16(Ag1, &As[0][0] + ld1);
  GLD16(Bg0, &Bs[0][0] + ld0); GLD16(Bg1, &Bs[0][0] + ld1);
  GLD16(Ag0 + 32, &As[1][0] + ld0); GLD16(Ag1 + 32, &As[1][0] + ld1);
  GLD16(Bg0 + 32, &Bs[1][0] + ld0); GLD16(Bg1 + 32, &Bs[1][0] + ld1);

  // tiles 0..29 (prefetch i+2), then peeled 30 (no prefetch) and 31 (vmcnt 0)
  for (int ii = 0; ii < 15; ++ii) {
    const int kk2a = ii * 64 + 64;
    GEMM_TILE(0, WAITV4, true, kk2a);
    GEMM_TILE(1, WAITV4, true, kk2a + 32);
  }
  GEMM_TILE(0, WAITV4, false, 0);
  GEMM_TILE(1, WAITV0, false, 0);

  // epilogue: C row = quad*4+reg, col = l16 (m89-verified C/D layout)
  if (z < 2) {
    const float* cosb = (z == 0) ? cos_q : cos_k;
    const float* sinb = (z == 0) ? sin_q : sin_k;
    bf16_t* out = (z == 0) ? qtb : ktb;
    const int h = (n0 + wn) >> 6;
#pragma unroll
    for (int i = 0; i < 4; ++i) {
#pragma unroll
      for (int j = 0; j < 2; ++j) {
        const int hd1 = j * 16 + l16;
        const int hd2 = hd1 + 32;
        const float bn1 = bias[n0 + wn + hd1];
        const float bn2 = bias[n0 + wn + hd2];
#pragma unroll
        for (int r = 0; r < 4; ++r) {
          const int m = m0 + wm + i * 16 + quad * 4 + r;
          const int b = m >> 11, l = m & (LSEQ - 1);
          const size_t cb = ((size_t)b * LSEQ + l) * HD;
          const float x1 = (float)(bf16_t)(acc[i][j][r] + bn1);
          const float x2 = (float)(bf16_t)(acc[i][j + 2][r] + bn2);
          const float c1 = cosb[cb + hd1], s1 = sinb[cb + hd1];
          const float c2 = cosb[cb + hd2], s2 = sinb[cb + hd2];
          bf16_t* dst = out + (((size_t)(b * NH + h)) * LSEQ + l) * HD;
          dst[hd1] = (bf16_t)(x1 * c1 - x2 * s1);
          dst[hd2] = (bf16_t)(x2 * c2 + x1 * s2);
        }
      }
    }
  } else {
#pragma unroll
    for (int i = 0; i < 4; ++i) {
      const int mb = m0 + wm + i * 16 + quad * 4;
      const int b = mb >> 11, l = mb & (LSEQ - 1);
#pragma unroll
      for (int j = 0; j < 4; ++j) {
        const int n = n0 + wn + j * 16 + l16;
        const int h = n >> 6, hd = n & (HD - 1);
        const float bn = bias[n];
        bf16x4 pk;
#pragma unroll
        for (int r = 0; r < 4; ++r) pk[r] = (bf16_t)(acc[i][j][r] + bn);
        *(bf16x4*)(vtb + (((size_t)(b * NH + h)) * HD + hd) * LSEQ + l) = pk;
      }
    }
  }
}

// ---------------------------------------------------------------------------
// Out projection: C = A * Wo^T + bo, f32 store (round-8: swizzle + T4 pipeline)
// ---------------------------------------------------------------------------
__global__ __launch_bounds__(256) void out_gemm_kernel(const bf16_t* __restrict__ A,
                                                       const bf16_t* __restrict__ Bw,
                                                       const float* __restrict__ bias,
                                                       float* __restrict__ out) {
  __shared__ bf16_t As[2][128 * 32];
  __shared__ bf16_t Bs[2][128 * 32];
  const int tid  = threadIdx.x;
  const int wave = tid >> 6, lane = tid & 63;
  const int quad = lane >> 4, l16 = lane & 15;
  const int m0 = blockIdx.x * 128, n0 = blockIdx.y * 128;
  const int wm = (wave >> 1) * 64, wn = (wave & 1) * 64;

  f32x4 acc[4][4];
#pragma unroll
  for (int i = 0; i < 4; ++i)
#pragma unroll
    for (int j = 0; j < 4; ++j) acc[i][j] = (f32x4){0.f, 0.f, 0.f, 0.f};

  const int srow = lane >> 2;
  const int scol = ((lane & 3) ^ ((lane >> 3) & 3)) * 8;
  const int c0 = wave * 2, c1 = c0 + 1;
  const int r0 = c0 * 16 + srow, r1 = c1 * 16 + srow;
  const bf16_t* Ag0 = A  + (size_t)(m0 + r0) * DM + scol;
  const bf16_t* Ag1 = A  + (size_t)(m0 + r1) * DM + scol;
  const bf16_t* Bg0 = Bw + (size_t)(n0 + r0) * DM + scol;
  const bf16_t* Bg1 = Bw + (size_t)(n0 + r1) * DM + scol;
  const int ld0 = c0 * 512, ld1 = c1 * 512;
  const int fcol = ((quad ^ ((l16 >> 1) & 3)) << 3);

  GLD16(Ag0, &As[0][0] + ld0); GLD16(Ag1, &As[0][0] + ld1);
  GLD16(Bg0, &Bs[0][0] + ld0); GLD16(Bg1, &Bs[0][0] + ld1);
  GLD16(Ag0 + 32, &As[1][0] + ld0); GLD16(Ag1 + 32, &As[1][0] + ld1);
  GLD16(Bg0 + 32, &Bs[1][0] + ld0); GLD16(Bg1 + 32, &Bs[1][0] + ld1);

  for (int ii = 0; ii < 15; ++ii) {
    const int kk2a = ii * 64 + 64;
    GEMM_TILE(0, WAITV4, true, kk2a);
    GEMM_TILE(1, WAITV4, true, kk2a + 32);
  }
  GEMM_TILE(0, WAITV4, false, 0);
  GEMM_TILE(1, WAITV0, false, 0);

#pragma unroll
  for (int i = 0; i < 4; ++i)
#pragma unroll
    for (int j = 0; j < 4; ++j) {
      const int n  = n0 + wn + j * 16 + l16;
      const float bn = bias[n];
#pragma unroll
      for (int r = 0; r < 4; ++r) {
        const int m = m0 + wm + i * 16 + quad * 4 + r;
        out[(size_t)m * DM + n] = acc[i][j][r] + bn;
      }
    }
}

// ---------------------------------------------------------------------------
// Flash attention v6 (unchanged): grid (LSEQ/128, B*NH), 256 threads
// (4 waves x 32 q-rows). sigma-permuted K staging, in-register P transpose,
// XOR swizzle, 2-deep buffer, mask pre-scan, l via ones-MFMA.
// ---------------------------------------------------------------------------
__global__ __launch_bounds__(256, 4) void attn_kernel(const bf16_t* __restrict__ qt,
                                                      const bf16_t* __restrict__ kt,
                                                      const bf16_t* __restrict__ vt,
                                                      const unsigned char* __restrict__ mask,
                                                      bf16_t* __restrict__ ctx) {
  __shared__ bf16_t Kl[2][64 * 64];        // [pos][d], col-blocks swizzled by pos&7
  __shared__ bf16_t Vl[2][64 * 64];        // [d][kk],  col-blocks swizzled by d&7
  __shared__ int mflag;
  const int bh = blockIdx.y;
  const int b = bh >> 4, h = bh & (NH - 1);
  const int q0 = blockIdx.x * 128;
  const int tid = threadIdx.x;
  const int wave = tid >> 6, lane = tid & 63;
  const int quad = lane >> 4, l16 = lane & 15;
  const float scale_l2e = 0.125f * 1.44269504f;  // HD^-0.5 * log2(e)

  const bf16_t* kbase = kt + (size_t)bh * LSEQ * HD;
  const bf16_t* vbase = vt + (size_t)bh * HD * LSEQ;
  const unsigned char* mrow = mask + (size_t)b * LSEQ;

  if (tid == 0) mflag = 0;
  __syncthreads();
  // mask pre-scan: 256 threads x 8B = entire 2048B row
  {
    const uint64_t mw = ((const uint64_t*)mrow)[tid];
    if (mw != 0) atomicOr(&mflag, 1);
  }

  // Q fragments (m=l16, k=quad*8+e), used as B-operand of swapped QK^T
  bf16x8 qa[2][2];
#pragma unroll
  for (int u = 0; u < 2; ++u) {
    const bf16_t* qrow = qt + (((size_t)bh * LSEQ) + q0 + wave * 32 + u * 16 + l16) * HD;
    qa[u][0] = *(const bf16x8*)(qrow + quad * 8);
    qa[u][1] = *(const bf16x8*)(qrow + 32 + quad * 8);
  }

  f32x4 O[2][4];
  f32x4 Ol[2];
#pragma unroll
  for (int u = 0; u < 2; ++u) {
    Ol[u] = (f32x4){0.f, 0.f, 0.f, 0.f};
#pragma unroll
    for (int j = 0; j < 4; ++j) O[u][j] = (f32x4){0.f, 0.f, 0.f, 0.f};
  }
  bf16x8 ones;
#pragma unroll
  for (int e = 0; e < 8; ++e) ones[e] = (bf16_t)1.0f;

  // --- hoisted per-lane offsets ---
  const int srow8 = lane >> 3;  // 0..7 within 8-row chunk
  const int scb   = lane & 7;   // LDS col-block position
  const int c0 = wave * 2, c1 = c0 + 1;
  const int p0 = c0 * 8 + srow8, p1 = p0 + 8;
  const int g0 = (scb ^ srow8) * 8;   // p&7 == srow8 for both chunks
  const int sig0 = ((p0 >> 5) << 5) | (((p0 >> 2) & 3) << 3) | (((p0 >> 4) & 1) << 2) | (p0 & 3);
  const int sig1 = ((p1 >> 5) << 5) | (((p1 >> 2) & 3) << 3) | (((p1 >> 4) & 1) << 2) | (p1 & 3);
  const int kgo0 = sig0 * HD + g0, kgo1 = sig1 * HD + g0;      // K global lane offsets
  const int vgo0 = p0 * LSEQ + g0, vgo1 = p1 * LSEQ + g0;      // V global lane offsets
  const int ld0 = c0 * 512, ld1 = c1 * 512;                    // LDS dst offsets

  // fragment-read offsets: sw = (j*16+l16)&7 == l16&7 for all j
  const int sw  = l16 & 7;
  const int oA  = l16 * 64 + ((quad ^ sw) << 3);
  const int oB  = l16 * 64 + (((quad + 4) ^ sw) << 3);

  // prologue: stage tile 0 into buffer 0 (K rows sigma-permuted)
  GLD16(kbase + kgo0, &Kl[0][0] + ld0);
  GLD16(kbase + kgo1, &Kl[0][0] + ld1);
  GLD16(vbase + vgo0, &Vl[0][0] + ld0);
  GLD16(vbase + vgo1, &Vl[0][0] + ld1);
  __syncthreads();
  const bool has_mask = (mflag != 0);

  int cur = 0;
  for (int t = 0; t < 32; ++t) {
    const int k0 = t * 64;

    // prefetch next tile into the other buffer (hidden under this tile's work)
    if (t < 31) {
      const int k0n = k0 + 64;
      bf16_t* Kd = &Kl[cur ^ 1][0];
      bf16_t* Vd = &Vl[cur ^ 1][0];
      GLD16(kbase + (size_t)k0n * HD + kgo0, Kd + ld0);
      GLD16(kbase + (size_t)k0n * HD + kgo1, Kd + ld1);
      GLD16(vbase + (size_t)(vgo0 + k0n), Vd + ld0);
      GLD16(vbase + (size_t)(vgo1 + k0n), Vd + ld1);
    }

    const bf16_t* Kc = &Kl[cur][0];
    const bf16_t* Vc = &Vl[cur][0];

    // S = exp2(scale*log2e * K.Q^T), swapped operands
    f32x4 S[2][4];
#pragma unroll
    for (int j = 0; j < 4; ++j) {
      const bf16x8 kb0 = *(const bf16x8*)(Kc + oA + j * 1024);
      const bf16x8 kb1 = *(const bf16x8*)(Kc + oB + j * 1024);
#pragma unroll
      for (int u = 0; u < 2; ++u) {
        f32x4 a = (f32x4){0.f, 0.f, 0.f, 0.f};
        a = mfma_16x16x32(kb0, qa[u][0], a);
        a = mfma_16x16x32(kb1, qa[u][1], a);
#pragma unroll
        for (int r = 0; r < 4; ++r)
          S[u][j][r] = __builtin_amdgcn_exp2f(a[r] * scale_l2e);
      }
    }

    // masked positions -> P = 0 (block-uniform skip when mask all-false)
    if (has_mask) {
      const uint64_t mlo = *(const uint64_t*)(mrow + k0 + quad * 8);
      const uint64_t mhi = *(const uint64_t*)(mrow + k0 + 32 + quad * 8);
      if (!__all((mlo | mhi) == 0)) {
#pragma unroll
        for (int j = 0; j < 4; ++j) {
          const uint64_t mm = (j & 2) ? mhi : mlo;
#pragma unroll
          for (int r = 0; r < 4; ++r)
            if ((mm >> (((j & 1) * 4 + r) * 8)) & 0xff) {
              S[0][j][r] = 0.f;
              S[1][j][r] = 0.f;
            }
        }
      }
    }

    // in-register P transpose: slot s=f*32+quad*8+e holds orig k=s
    bf16x8 pa[2][2];
#pragma unroll
    for (int u = 0; u < 2; ++u)
#pragma unroll
      for (int f = 0; f < 2; ++f)
#pragma unroll
        for (int e = 0; e < 8; ++e)
          pa[u][f][e] = (bf16_t)S[u][2 * f + (e >> 2)][e & 3];

    // l via ones-MFMA: every lane accumulates l(q) for q=quad*4+r in Ol[u][r]
#pragma unroll
    for (int u = 0; u < 2; ++u) {
      Ol[u] = mfma_16x16x32(pa[u][0], ones, Ol[u]);
      Ol[u] = mfma_16x16x32(pa[u][1], ones, Ol[u]);
    }

    // O += P * V  (B-operand from Vl [d][kk], swizzled); V frags reused for both u
#pragma unroll
    for (int jd = 0; jd < 4; ++jd) {
      const bf16x8 vb0 = *(const bf16x8*)(Vc + oA + jd * 1024);
      const bf16x8 vb1 = *(const bf16x8*)(Vc + oB + jd * 1024);
#pragma unroll
      for (int u = 0; u < 2; ++u) {
        O[u][jd] = mfma_16x16x32(pa[u][0], vb0, O[u][jd]);
        O[u][jd] = mfma_16x16x32(pa[u][1], vb1, O[u][jd]);
      }
    }

    // one barrier per tile: waves done reading buf[cur] AND (implicit
    // vmcnt(0)+lgkmcnt(0) drain) next-tile prefetch landed in buf[cur^1]
    if (t < 31) __syncthreads();
    cur ^= 1;
  }

  // epilogue: normalize and write ctx [B, LSEQ, NH*HD] bf16 (token-major)
#pragma unroll
  for (int u = 0; u < 2; ++u) {
    f32x4 linv;
#pragma unroll
    for (int r = 0; r < 4; ++r) linv[r] = 1.0f / Ol[u][r];
#pragma unroll
    for (int jd = 0; jd < 4; ++jd)
#pragma unroll
      for (int r = 0; r < 4; ++r) {
        const int l = q0 + wave * 32 + u * 16 + quad * 4 + r;
        const int d = h * HD + jd * 16 + l16;
        const float o = O[u][jd][r] * linv[r];
        ctx[((size_t)b * LSEQ + l) * DM + d] = (bf16_t)o;
      }
  }
}

// ---------------------------------------------------------------------------
extern "C" void kernel_launch(void* const* d_in, const int* in_sizes, int n_in,
                              void* d_out, int out_size, void* d_ws, size_t ws_size,
                              hipStream_t stream) {
  (void)in_sizes; (void)n_in; (void)out_size; (void)ws_size;
  const float* query = (const float*)d_in[0];
  const float* key   = (const float*)d_in[1];
  const float* value = (const float*)d_in[2];
  const float* cos_q = (const float*)d_in[3];
  const float* sin_q = (const float*)d_in[4];
  const float* cos_k = (const float*)d_in[5];
  const float* sin_k = (const float*)d_in[6];
  const unsigned char* mask = (const unsigned char*)d_in[7];
  const float* Wq = (const float*)d_in[8];
  const float* bq = (const float*)d_in[9];
  const float* Wk = (const float*)d_in[10];
  const float* bk = (const float*)d_in[11];
  const float* Wv = (const float*)d_in[12];
  const float* bv = (const float*)d_in[13];
  const float* Wo = (const float*)d_in[14];
  const float* bo = (const float*)d_in[15];
  float* out = (float*)d_out;

  const size_t ACT = (size_t)TOKENS * DM;  // 8388608
  const size_t WEL = (size_t)DM * DM;      // 1048576

  bf16_t* p   = (bf16_t*)d_ws;
  bf16_t* xq  = p; p += ACT;    // xq,xk,xv contiguous (cast3 dst / qkv A base)
  bf16_t* xk  = p; p += ACT;
  bf16_t* xv  = p; p += ACT;
  bf16_t* wqb = p; p += WEL;    // wqb..wob contiguous (cast4 dst / qkv W base)
  bf16_t* wkb = p; p += WEL;
  bf16_t* wvb = p; p += WEL;
  bf16_t* wob = p; p += WEL;
  bf16_t* qtb = p; p += ACT;
  bf16_t* ktb = p; p += ACT;
  bf16_t* vtb = p; p += ACT;
  bf16_t* ctx = xk;  // alias: xk dead after qkv proj
  (void)xv; (void)wkb; (void)wvb;

  // casts (f32 -> bf16): 2 dispatches
  cast3_kernel<<<dim3((int)(ACT / 1024), 3), 256, 0, stream>>>(query, key, value, xq, (int)ACT);
  cast4_kernel<<<dim3((int)(WEL / 1024), 4), 256, 0, stream>>>(Wq, Wk, Wv, Wo, wqb, (int)WEL);

  // fused q/k/v projections (one dispatch, z = which projection)
  qkv_proj_kernel<<<dim3(TOKENS / 128, DM / 128, 3), 256, 0, stream>>>(
      xq, wqb, bq, bk, bv, cos_q, sin_q, cos_k, sin_k, qtb, ktb, vtb);

  // flash attention -> ctx [B, LSEQ, DM] bf16
  attn_kernel<<<dim3(LSEQ / 128, B_DIM * NH), 256, 0, stream>>>(qtb, ktb, vtb, mask, ctx);

  // output projection -> f32 d_out
  out_gemm_kernel<<<dim3(TOKENS / 128, DM / 128), 256, 0, stream>>>(ctx, wob, bo, out);
}